// Round 3
// baseline (135.042 us; speedup 1.0000x reference)
//
#include <hip/hip_runtime.h>
#include <hip/hip_bf16.h>

// GCN layer: out[c] = bias + dis[c]*(dis[c]*h[c] + sum_{r in in(c)} dis[r]*h[r]),
//            h = X @ W (bf16, UNSCALED), dis = rsqrt(deg+1).
// N=50000, E=800000, D=64, fp32 in/out.
// R17: break the gemm->dis dependency (hs stores unscaled bf16(X@W); gather
//      applies dis[r] per edge via wave-uniform scalar load + fma). This lets
//      hist and gemm share ONE dispatch (128 hist blocks + 196 4-tile gemm
//      blocks, 84KB union LDS) -> 4 dispatches total. offs finalize moves back
//      into bucket (R14-proven 196-int scan, 1KB), keeping R15's u8 counters.

constexpr int N_NODES = 50000;
constexpr int N_EDGES = 800000;
constexpr int D = 64;
constexpr int NB_SCAN = (N_NODES + 255) / 256;  // 196

constexpr int B_SLICE = 64;                  // edge slices
constexpr int SLICE = N_EDGES / B_SLICE;     // 12500 (exact)
constexpr int PACK8 = N_NODES / 4;           // 12500 u32 words (u8 x4)
constexpr int QUAR = N_NODES / 4;            // 12500 nodes per bucket quarter
constexpr int NB_GEMM = (N_NODES / 64 + 1 + 3) / 4;  // 196 blocks x 4 tiles >= 782

static __device__ __forceinline__ unsigned short f2bf(float f) {
    unsigned u = __float_as_uint(f);
    unsigned r = (u + 0x7fffu + ((u >> 16) & 1u)) >> 16;  // RNE
    return (unsigned short)r;
}
static __device__ __forceinline__ float bf2f(unsigned short s) {
    return __uint_as_float((unsigned)s << 16);
}

struct GemmLds {
    float Ws[64][64];      // 16 KB, shared by all 4 groups
    float Xs[4][64][68];   // 69.6 KB, one [64][68] per 256-thread group
};
constexpr size_t HIST_LDS = (size_t)PACK8 * 4;          // 50000
constexpr size_t FUSED_LDS = sizeof(GemmLds) > HIST_LDS ? sizeof(GemmLds) : HIST_LDS;

// ---- 1. fused: blocks [0,128) = per-slice u8 histograms (R12 proven);
//                blocks [128,324) = 4x 64x64 gemm tiles, hs = bf16(X@W) ----
__global__ __launch_bounds__(1024, 4) void fused_hist_gemm(
        const int* __restrict__ ei, unsigned* __restrict__ bh,
        const float* __restrict__ x, const float* __restrict__ W,
        unsigned short* __restrict__ hs) {
    __shared__ __align__(16) char ldsraw[FUSED_LDS];
    const int b = blockIdx.x;
    const int t = threadIdx.x;

    if (b < 2 * B_SLICE) {  // ---------- hist role ----------
        unsigned* loc = (unsigned*)ldsraw;
        int s = b & (B_SLICE - 1);
        const int* arr = (b < B_SLICE) ? ei : ei + N_EDGES;
        for (int w = t; w < PACK8; w += 1024) loc[w] = 0;
        __syncthreads();
        const int* p = arr + s * SLICE;
        for (int i = t; i < SLICE; i += 1024) {
            int k = p[i];
            atomicAdd(&loc[k >> 2], 1u << (8 * (k & 3)));  // LDS atomic
        }
        __syncthreads();
        unsigned* dst = bh + (size_t)b * PACK8;
        for (int w = t; w < PACK8; w += 1024) dst[w] = loc[w];
    } else {  // ---------- gemm role: 4 independent 64x64 tiles ----------
        GemmLds* g = (GemmLds*)ldsraw;
        const int grp = t >> 8, t256 = t & 255;
        const int tb = (b - 2 * B_SLICE) * 4 + grp;  // 0..783; >=782 fully guarded
        const int n0 = tb * 64;

        ((float4*)g->Ws)[t] = ((const float4*)W)[t];  // 1024 float4 = 16KB exact

        float (*Xs)[68] = g->Xs[grp];
        const float4* x4 = (const float4*)(x + (size_t)n0 * D);
#pragma unroll
        for (int i = 0; i < 4; ++i) {
            int f = t256 + i * 256;
            int r = f >> 4, c = (f & 15) << 2;
            float4 v = make_float4(0.f, 0.f, 0.f, 0.f);
            if (n0 + r < N_NODES) v = x4[f];
            Xs[r][c] = v.x; Xs[r][c + 1] = v.y; Xs[r][c + 2] = v.z; Xs[r][c + 3] = v.w;
        }
        __syncthreads();

        int tx = t256 & 15, ty = t256 >> 4;
        float acc[4][4] = {};
#pragma unroll 8
        for (int k = 0; k < D; ++k) {
            float a[4], bb[4];
#pragma unroll
            for (int i = 0; i < 4; ++i) a[i] = Xs[ty * 4 + i][k];
#pragma unroll
            for (int jj = 0; jj < 4; ++jj) bb[jj] = g->Ws[k][tx * 4 + jj];
#pragma unroll
            for (int i = 0; i < 4; ++i)
#pragma unroll
                for (int jj = 0; jj < 4; ++jj)
                    acc[i][jj] = fmaf(a[i], bb[jj], acc[i][jj]);
        }

#pragma unroll
        for (int i = 0; i < 4; ++i) {
            int r = ty * 4 + i;
            if (n0 + r < N_NODES) {
                ushort4 v;
                v.x = f2bf(acc[i][0]); v.y = f2bf(acc[i][1]);
                v.z = f2bf(acc[i][2]); v.w = f2bf(acc[i][3]);
                *(ushort4*)(hs + (size_t)(n0 + r) * D + tx * 4) = v;
            }
        }
    }
}

// ---- 2. reduce + dis + inline bs8 + block-local scan (R12 proven) ----
__global__ __launch_bounds__(256) void reduce_scan_kernel(const unsigned* __restrict__ bh,
                                                          float* __restrict__ dis,
                                                          int* __restrict__ offs_local,
                                                          int* __restrict__ partials,
                                                          unsigned char* __restrict__ bs8) {
    int t = threadIdx.x;
    int i = blockIdx.x * 256 + t;
    unsigned cl = 0;
    if (i < N_NODES) {
        const int w = i >> 2;
        const unsigned sh = 8 * (i & 3);
        const unsigned* prow = bh + w;
        unsigned dl = 0;
#pragma unroll
        for (int g = 0; g < 4; ++g) {
            unsigned vr[16];
#pragma unroll
            for (int k = 0; k < 16; ++k) vr[k] = prow[(size_t)(g * 16 + k) * PACK8];
#pragma unroll
            for (int k = 0; k < 16; ++k) dl += (vr[k] >> sh) & 0xffu;
        }
        dis[i] = rsqrtf((float)dl + 1.0f);  // +1 self loop
        const unsigned* pcol = bh + (size_t)B_SLICE * PACK8 + w;
#pragma unroll
        for (int g = 0; g < 4; ++g) {
            unsigned vr[16];
#pragma unroll
            for (int k = 0; k < 16; ++k) vr[k] = pcol[(size_t)(g * 16 + k) * PACK8];
#pragma unroll
            for (int k = 0; k < 16; ++k) {
                bs8[(size_t)(g * 16 + k) * N_NODES + i] = (unsigned char)cl;  // rel start
                cl += (vr[k] >> sh) & 0xffu;
            }
        }
    }
    __shared__ int s[256];
    s[t] = (int)cl;
    __syncthreads();
    for (int d = 1; d < 256; d <<= 1) {
        int u = (t >= d) ? s[t - d] : 0;
        __syncthreads();
        s[t] += u;
        __syncthreads();
    }
    if (i < N_NODES) offs_local[i] = s[t] - (int)cl;
    if (t == 255) partials[blockIdx.x] = s[t];
}

// ---- 3. bucket: u8-packed LDS position counters (R15) + per-block 196-scan
//         of partials (R14, 1KB LDS). base = pref[c>>8] + offs_local[c]
//         (offs_local L2-hot 200KB). s==0 blocks write offs (+sentinel). ----
__global__ __launch_bounds__(1024) void bucket_det_kernel(const int* __restrict__ ei,
                                                          const int* __restrict__ offs_local,
                                                          const int* __restrict__ partials,
                                                          const unsigned char* __restrict__ bs8,
                                                          int* __restrict__ csr,
                                                          int* __restrict__ offs) {
    __shared__ unsigned pos[QUAR / 4];  // 12.5 KB, u8 x4 per word
    __shared__ int pref[256];           // exclusive-scanned partials
    const int t = threadIdx.x;

    if (t < 256) pref[t] = (t < NB_SCAN) ? partials[t] : 0;
    __syncthreads();
    for (int d = 1; d < 256; d <<= 1) {
        int u = 0;
        if (t < 256 && t >= d) u = pref[t - d];
        __syncthreads();
        if (t < 256) pref[t] += u;
        __syncthreads();
    }
    if (t < 256) {
        int inc = pref[t];
        int own = (t < NB_SCAN) ? partials[t] : 0;
        pref[t] = inc - own;  // exclusive
    }
    __syncthreads();

    const int s = blockIdx.x >> 2;
    const int q = blockIdx.x & 3;
    const int c0 = q * QUAR;

    // init: rel8 start offsets for this (slice, quarter); both offsets %4==0
    const unsigned* rel32 = (const unsigned*)(bs8 + (size_t)s * N_NODES + c0);
    for (int w = t; w < QUAR / 4; w += 1024) pos[w] = rel32[w];

    if (s == 0) {  // block-uniform: write absolute offs for gather
        const int* olq = offs_local + c0;
        for (int w = t; w < QUAR; w += 1024) {
            int node = c0 + w;
            offs[node] = pref[node >> 8] + olq[w];
        }
        if (q == 3 && t == 0) offs[N_NODES] = N_EDGES;  // sentinel
    }
    __syncthreads();

    const int* rowp = ei + s * SLICE;
    const int* colp = ei + N_EDGES + s * SLICE;
    for (int i = t; i < SLICE; i += 1024) {
        int c = colp[i];
        unsigned cc = (unsigned)(c - c0);
        if (cc < (unsigned)QUAR) {
            int base = pref[c >> 8] + offs_local[c];  // L2-hot, independent of atomic
            unsigned old = atomicAdd(&pos[cc >> 2], 1u << (8 * (cc & 3)));
            unsigned rel = (old >> (8 * (cc & 3))) & 0xffu;
            csr[base + (int)rel] = rowp[i];
        }
    }
}

// ---- 4. gather: wave per node, scalar csr loads, MLP 16 (R12 proven);
//         per-row dis[r] applied here (wave-uniform scalar load + fma). ----
__global__ __launch_bounds__(256) void gather_kernel(const int* __restrict__ offs,
                                                     const int* __restrict__ csr,
                                                     const unsigned short* __restrict__ hs,
                                                     const float* __restrict__ dis,
                                                     const float* __restrict__ bias,
                                                     float* __restrict__ out) {
    int wave = threadIdx.x >> 6;
    int j = threadIdx.x & 63;
    int n = blockIdx.x * 4 + wave;
    if (n >= N_NODES) return;

    float dn = dis[n];
    float a[8];
    a[0] = dn * bf2f(hs[(size_t)n * D + j]);  // self loop dis[n]*h[n]
#pragma unroll
    for (int k = 1; k < 8; ++k) a[k] = 0.f;

    // wave-uniform (SGPR) csr addressing -> scalar loads, free broadcast
    int beg = __builtin_amdgcn_readfirstlane(offs[n]);
    int m   = __builtin_amdgcn_readfirstlane(offs[n + 1]) - beg;
    const int* p = csr + beg;

    int i = 0;
    for (; i + 16 <= m; i += 16) {
        int r[16];
        float dr[16];
        float v[16];
#pragma unroll
        for (int k = 0; k < 16; ++k) r[k] = p[i + k];
#pragma unroll
        for (int k = 0; k < 16; ++k) dr[k] = dis[r[k]];  // wave-uniform, L2-hot
#pragma unroll
        for (int k = 0; k < 16; ++k) v[k] = bf2f(hs[(size_t)r[k] * D + j]);  // 16 in flight
#pragma unroll
        for (int k = 0; k < 16; ++k) a[k & 7] = fmaf(v[k], dr[k], a[k & 7]);
    }
    for (; i + 4 <= m; i += 4) {
        int r0 = p[i], r1 = p[i + 1], r2 = p[i + 2], r3 = p[i + 3];
        a[0] = fmaf(bf2f(hs[(size_t)r0 * D + j]), dis[r0], a[0]);
        a[1] = fmaf(bf2f(hs[(size_t)r1 * D + j]), dis[r1], a[1]);
        a[2] = fmaf(bf2f(hs[(size_t)r2 * D + j]), dis[r2], a[2]);
        a[3] = fmaf(bf2f(hs[(size_t)r3 * D + j]), dis[r3], a[3]);
    }
    for (; i < m; ++i) {
        int r0 = p[i];
        a[1] = fmaf(bf2f(hs[(size_t)r0 * D + j]), dis[r0], a[1]);
    }
    float tot = ((a[0] + a[1]) + (a[2] + a[3])) + ((a[4] + a[5]) + (a[6] + a[7]));
    out[(size_t)n * D + j] = fmaf(dn, tot, bias[j]);
}

// ======================= fallback (atomic) build path =======================

__global__ __launch_bounds__(256, 4) void gemm_plain_kernel(const float* __restrict__ x,
                                                            const float* __restrict__ W,
                                                            unsigned short* __restrict__ hs) {
    __shared__ float Xs[64][68];
    __shared__ float Ws[64][64];
    int t = threadIdx.x;
    int n0 = blockIdx.x * 64;

    const float4* W4 = (const float4*)W;
    float4* Ws4 = (float4*)Ws;
#pragma unroll
    for (int i = 0; i < 4; ++i) Ws4[t + i * 256] = W4[t + i * 256];

    const float4* x4 = (const float4*)(x + (size_t)n0 * D);
#pragma unroll
    for (int i = 0; i < 4; ++i) {
        int f = t + i * 256;
        int r = f >> 4, c = (f & 15) << 2;
        float4 v = make_float4(0.f, 0.f, 0.f, 0.f);
        if (n0 + r < N_NODES) v = x4[f];
        Xs[r][c] = v.x; Xs[r][c + 1] = v.y; Xs[r][c + 2] = v.z; Xs[r][c + 3] = v.w;
    }
    __syncthreads();

    int tx = t & 15, ty = t >> 4;
    float acc[4][4] = {};
#pragma unroll 8
    for (int k = 0; k < D; ++k) {
        float a[4], bb[4];
#pragma unroll
        for (int i = 0; i < 4; ++i) a[i] = Xs[ty * 4 + i][k];
#pragma unroll
        for (int jj = 0; jj < 4; ++jj) bb[jj] = Ws[k][tx * 4 + jj];
#pragma unroll
        for (int i = 0; i < 4; ++i)
#pragma unroll
            for (int jj = 0; jj < 4; ++jj)
                acc[i][jj] = fmaf(a[i], bb[jj], acc[i][jj]);
    }

#pragma unroll
    for (int i = 0; i < 4; ++i) {
        int r = ty * 4 + i;
        if (n0 + r < N_NODES) {
            ushort4 v;
            v.x = f2bf(acc[i][0]); v.y = f2bf(acc[i][1]);
            v.z = f2bf(acc[i][2]); v.w = f2bf(acc[i][3]);
            *(ushort4*)(hs + (size_t)(n0 + r) * D + tx * 4) = v;
        }
    }
}

__global__ void histf_kernel(const int* __restrict__ row, const int* __restrict__ col,
                             int* __restrict__ degi, int* __restrict__ cnt) {
    int e = blockIdx.x * blockDim.x + threadIdx.x;
    if (e < N_EDGES) {
        atomicAdd(&degi[row[e]], 1);
        atomicAdd(&cnt[col[e]], 1);
    }
}

__global__ void disf_kernel(int* __restrict__ degi) {
    int i = blockIdx.x * blockDim.x + threadIdx.x;
    if (i < N_NODES) {
        float d = (float)degi[i] + 1.0f;
        ((float*)degi)[i] = rsqrtf(d);
    }
}

__global__ void block_scan_kernel(const int* __restrict__ cnt, int* __restrict__ offs,
                                  int* __restrict__ partials) {
    __shared__ int s[256];
    int t = threadIdx.x;
    int i = blockIdx.x * 256 + t;
    int v = (i < N_NODES) ? cnt[i] : 0;
    s[t] = v;
    __syncthreads();
    for (int d = 1; d < 256; d <<= 1) {
        int u = (t >= d) ? s[t - d] : 0;
        __syncthreads();
        s[t] += u;
        __syncthreads();
    }
    if (i < N_NODES) offs[i] = s[t] - v;
    if (t == 255) partials[blockIdx.x] = s[t];
}

__global__ void scan_partials_kernel(int* __restrict__ partials) {
    __shared__ int s[256];
    int t = threadIdx.x;
    int v = (t < NB_SCAN) ? partials[t] : 0;
    s[t] = v;
    __syncthreads();
    for (int d = 1; d < 256; d <<= 1) {
        int u = (t >= d) ? s[t - d] : 0;
        __syncthreads();
        s[t] += u;
        __syncthreads();
    }
    if (t < NB_SCAN) partials[t] = s[t] - v;
}

__global__ void add_off_kernel(int* __restrict__ offs, const int* __restrict__ partials) {
    int i = blockIdx.x * 256 + threadIdx.x;
    if (i < N_NODES) offs[i] += partials[blockIdx.x];
    if (i == 0) offs[N_NODES] = N_EDGES;
}

__global__ void bucket_fb_kernel(const int* __restrict__ row, const int* __restrict__ col,
                                 const int* __restrict__ offs, int* __restrict__ cur,
                                 int* __restrict__ csr) {
    int e = blockIdx.x * blockDim.x + threadIdx.x;
    if (e < N_EDGES) {
        int c = col[e];
        int pos = offs[c] + atomicAdd(&cur[c], 1);
        csr[pos] = row[e];
    }
}

// ======================= launch =======================

extern "C" void kernel_launch(void* const* d_in, const int* in_sizes, int n_in,
                              void* d_out, int out_size, void* d_ws, size_t ws_size,
                              hipStream_t stream) {
    const float* x    = (const float*)d_in[0];
    const int*   ei   = (const int*)d_in[1];
    const float* W    = (const float*)d_in[2];
    const float* bias = (const float*)d_in[3];
    float* out = (float*)d_out;

    // workspace layout (bytes):
    //   [0        ..   200000)  dis / degi (fallback)
    //   [200000   ..   400064)  offs (N+1 ints)
    //   [400064   ..   600064)  offs_local / cnt (fallback)
    //   [600064   ..   800064)  cur (fallback only)
    //   [800064   ..   801088)  partials
    //   [801088   ..  4001088)  csr (800000 x int)
    //   [4001088  .. 10401088)  hs (50000 x 64 bf16, UNSCALED)
    //   [10401088 .. 16801088)  bh (128 x 12500 u32, u8-packed)
    //   [16801088 .. 20001088)  bs8 (64 x 50000 u8, relative)
    char* ws = (char*)d_ws;
    float*          dis      = (float*)(ws + 0);
    int*            offs     = (int*)(ws + 200000);
    int*            offs_loc = (int*)(ws + 400064);
    int*            cur      = (int*)(ws + 600064);
    int*            partials = (int*)(ws + 800064);
    int*            csr      = (int*)(ws + 801088);
    unsigned short* hs       = (unsigned short*)(ws + 4001088);
    unsigned*       bh       = (unsigned*)(ws + 10401088);
    unsigned char*  bs8      = (unsigned char*)(ws + 16801088);

    const size_t WS_NEEDED = 20001088;

    if (ws_size >= WS_NEEDED) {
        fused_hist_gemm<<<2 * B_SLICE + NB_GEMM, 1024, 0, stream>>>(ei, bh, x, W, hs);
        reduce_scan_kernel<<<NB_SCAN, 256, 0, stream>>>(bh, dis, offs_loc, partials, bs8);
        bucket_det_kernel<<<4 * B_SLICE, 1024, 0, stream>>>(ei, offs_loc, partials, bs8,
                                                            csr, offs);
        gather_kernel<<<(N_NODES + 3) / 4, 256, 0, stream>>>(offs, csr, hs, dis, bias, out);
    } else {
        const int* row = ei;
        const int* col = ei + N_EDGES;
        int* degi = (int*)dis;
        int* cntf = offs_loc;
        hipMemsetAsync(ws, 0, 800064, stream);
        histf_kernel<<<(N_EDGES + 255) / 256, 256, 0, stream>>>(row, col, degi, cntf);
        disf_kernel<<<(N_NODES + 255) / 256, 256, 0, stream>>>(degi);
        block_scan_kernel<<<NB_SCAN, 256, 0, stream>>>(cntf, offs, partials);
        scan_partials_kernel<<<1, 256, 0, stream>>>(partials);
        add_off_kernel<<<NB_SCAN, 256, 0, stream>>>(offs, partials);
        gemm_plain_kernel<<<(N_NODES + 63) / 64, 256, 0, stream>>>(x, W, hs);
        bucket_fb_kernel<<<(N_EDGES + 255) / 256, 256, 0, stream>>>(row, col, offs, cur, csr);
        gather_kernel<<<(N_NODES + 3) / 4, 256, 0, stream>>>(offs, csr, hs, dis, bias, out);
    }
}